// Round 1
// baseline (73.709 us; speedup 1.0000x reference)
//
#include <hip/hip_runtime.h>
#include <math.h>

#define IN_FEAT 4096
#define OUT_FEAT 2048
#define NUM_KNOTS 10
#define DEGREE 3
#define N_BASIS 6          // NUM_KNOTS - DEGREE - 1
#define TI 256             // threads per block in main kernel (one output i per thread)
#define MAX_JCHUNK 512

// ---------------- Kernel 1: per-input basis + silu tables ----------------
__global__ void kan_basis_kernel(const float* __restrict__ x,
                                 float* __restrict__ s_tab,
                                 float* __restrict__ B_tab) {
    int j = blockIdx.x * blockDim.x + threadIdx.x;
    if (j >= IN_FEAT) return;
    float xv = x[j];
    float t[NUM_KNOTS];
#pragma unroll
    for (int m = 0; m < NUM_KNOTS; ++m)
        t[m] = -1.0f + (2.0f / 9.0f) * (float)m;
    float N[NUM_KNOTS - 1];
#pragma unroll
    for (int m = 0; m < NUM_KNOTS - 1; ++m)
        N[m] = (xv >= t[m] && xv < t[m + 1]) ? 1.0f : 0.0f;
#pragma unroll
    for (int d = 1; d <= DEGREE; ++d) {
#pragma unroll
        for (int m = 0; m + d < NUM_KNOTS - 1; ++m) {
            float ld = t[m + d] - t[m];
            float rd = t[m + d + 1] - t[m + 1];
            float lv = (ld > 0.0f) ? (xv - t[m]) / ld * N[m] : 0.0f;
            float rv = (rd > 0.0f) ? (t[m + d + 1] - xv) / rd * N[m + 1] : 0.0f;
            N[m] = lv + rv;   // N[m+1] still holds degree d-1 value when next m reads it
        }
    }
#pragma unroll
    for (int k = 0; k < N_BASIS; ++k)
        B_tab[j * N_BASIS + k] = N[k];
    s_tab[j] = xv / (1.0f + expf(-xv));   // silu
}

// ---------------- Kernel 2: partial sums over j-chunks ----------------
__global__ __launch_bounds__(TI) void kan_partial_kernel(
    const float* __restrict__ coeffs,     // [IN][OUT][N_BASIS]
    const float* __restrict__ bw,         // [IN][OUT]
    const float* __restrict__ s_tab,      // [IN]
    const float* __restrict__ B_tab,      // [IN][N_BASIS]
    float* __restrict__ partials,         // [nchunk][OUT]
    int jchunk) {
    __shared__ float Bs[MAX_JCHUNK * N_BASIS];
    __shared__ float ss[MAX_JCHUNK];
    const int tid = threadIdx.x;
    const int i = blockIdx.x * TI + tid;          // output column owned by this thread
    const int j0 = blockIdx.y * jchunk;

    for (int idx = tid; idx < jchunk * N_BASIS; idx += TI)
        Bs[idx] = B_tab[j0 * N_BASIS + idx];
    for (int idx = tid; idx < jchunk; idx += TI)
        ss[idx] = s_tab[j0 + idx];
    __syncthreads();

    float acc = 0.0f;
    const float* cp = coeffs + (size_t)j0 * (OUT_FEAT * N_BASIS) + (size_t)i * N_BASIS;
    const float* bp = bw + (size_t)j0 * OUT_FEAT + i;
#pragma unroll 4
    for (int j = 0; j < jchunk; ++j) {
        float2 c01 = *(const float2*)(cp + 0);
        float2 c23 = *(const float2*)(cp + 2);
        float2 c45 = *(const float2*)(cp + 4);
        const float* bj = &Bs[j * N_BASIS];   // same addr across lanes -> LDS broadcast
        acc += c01.x * bj[0] + c01.y * bj[1]
             + c23.x * bj[2] + c23.y * bj[3]
             + c45.x * bj[4] + c45.y * bj[5];
        acc += bp[0] * ss[j];
        cp += OUT_FEAT * N_BASIS;
        bp += OUT_FEAT;
    }
    partials[(size_t)blockIdx.y * OUT_FEAT + i] = acc;
}

// ---------------- Kernel 3: deterministic reduce ----------------
__global__ void kan_reduce_kernel(const float* __restrict__ partials,
                                  float* __restrict__ out, int nchunk) {
    int i = blockIdx.x * blockDim.x + threadIdx.x;
    if (i >= OUT_FEAT) return;
    float acc = 0.0f;
    for (int c = 0; c < nchunk; ++c)
        acc += partials[(size_t)c * OUT_FEAT + i];
    out[i] = acc;
}

extern "C" void kernel_launch(void* const* d_in, const int* in_sizes, int n_in,
                              void* d_out, int out_size, void* d_ws, size_t ws_size,
                              hipStream_t stream) {
    const float* x      = (const float*)d_in[0];   // [4096]
    const float* coeffs = (const float*)d_in[1];   // [4096][2048][6]
    const float* bw     = (const float*)d_in[2];   // [4096][2048]
    float* out = (float*)d_out;                    // [2048] fp32

    float* s_tab    = (float*)d_ws;                       // 4096 floats
    float* B_tab    = s_tab + IN_FEAT;                    // 4096*6 floats
    float* partials = B_tab + IN_FEAT * N_BASIS;          // nchunk*2048 floats

    // pick nchunk (power of two) that fits the workspace; 128 expected
    size_t head_floats = (size_t)IN_FEAT * (N_BASIS + 1);
    size_t avail = (ws_size / 4 > head_floats) ? ws_size / 4 - head_floats : 0;
    int nchunk = 128;
    while (nchunk > 8 && (size_t)nchunk * OUT_FEAT > avail) nchunk >>= 1;
    int jchunk = IN_FEAT / nchunk;                        // 32 in the expected case
    if (jchunk > MAX_JCHUNK) { jchunk = MAX_JCHUNK; nchunk = IN_FEAT / jchunk; }

    kan_basis_kernel<<<IN_FEAT / 256, 256, 0, stream>>>(x, s_tab, B_tab);

    dim3 grid(OUT_FEAT / TI, nchunk);
    kan_partial_kernel<<<grid, TI, 0, stream>>>(coeffs, bw, s_tab, B_tab, partials, jchunk);

    kan_reduce_kernel<<<(OUT_FEAT + 255) / 256, 256, 0, stream>>>(partials, out, nchunk);
}

// Round 2
// 42.633 us; speedup vs baseline: 1.7289x; 1.7289x over previous
//
#include <hip/hip_runtime.h>
#include <math.h>

#define IN_FEAT 4096
#define OUT_FEAT 2048
#define NUM_KNOTS 10
#define DEGREE 3
#define N_BASIS 6            // NUM_KNOTS - DEGREE - 1

#define TI 256               // threads per block (main kernel)
#define OPT 2                // outputs per thread
#define IBLK (TI * OPT)      // 512 outputs per block
#define JCHUNK 16            // input rows per chunk
#define NCHUNK (IN_FEAT / JCHUNK)   // 256
#define G1 16                // reduce stage-1 groups (NCHUNK/G1 chunks each)

// ---------------- fused: basis (per chunk) + partial dot ----------------
__global__ __launch_bounds__(TI) void kan_partial_kernel(
    const float* __restrict__ coeffs,    // [IN][OUT][N_BASIS]
    const float* __restrict__ bw,        // [IN][OUT]
    const float* __restrict__ x,         // [IN]
    float* __restrict__ partials) {      // [NCHUNK][OUT]
    __shared__ float4 w4[JCHUNK][2];     // {B0..B3},{B4,B5,silu,pad} per j
    const int tid = threadIdx.x;
    const int j0 = blockIdx.y * JCHUNK;

    if (tid < JCHUNK) {
        float xv = x[j0 + tid];
        float t[NUM_KNOTS];
#pragma unroll
        for (int m = 0; m < NUM_KNOTS; ++m)
            t[m] = -1.0f + (2.0f / 9.0f) * (float)m;
        float N[NUM_KNOTS - 1];
#pragma unroll
        for (int m = 0; m < NUM_KNOTS - 1; ++m)
            N[m] = (xv >= t[m] && xv < t[m + 1]) ? 1.0f : 0.0f;
#pragma unroll
        for (int d = 1; d <= DEGREE; ++d) {
#pragma unroll
            for (int m = 0; m + d < NUM_KNOTS - 1; ++m) {
                float ld = t[m + d] - t[m];
                float rd = t[m + d + 1] - t[m + 1];
                float lv = (ld > 0.0f) ? (xv - t[m]) / ld * N[m] : 0.0f;
                float rv = (rd > 0.0f) ? (t[m + d + 1] - xv) / rd * N[m + 1] : 0.0f;
                N[m] = lv + rv;
            }
        }
        float* wp = (float*)&w4[tid][0];
#pragma unroll
        for (int k = 0; k < N_BASIS; ++k) wp[k] = N[k];
        wp[6] = xv / (1.0f + expf(-xv));   // silu
        wp[7] = 0.0f;
    }
    __syncthreads();

    const int i0 = blockIdx.x * IBLK + tid * OPT;     // first of this thread's 2 outputs
    const float4* cp = (const float4*)(coeffs + ((size_t)j0 * OUT_FEAT + i0) * N_BASIS);
    const float2* bp = (const float2*)(bw + (size_t)j0 * OUT_FEAT + i0);

    float acc0 = 0.0f, acc1 = 0.0f;
#pragma unroll 4
    for (int j = 0; j < JCHUNK; ++j) {
        float4 a = cp[0];                 // i0:   c0 c1 c2 c3
        float4 b = cp[1];                 //       c4 c5 | i0+1: c0 c1
        float4 c = cp[2];                 //       c2 c3 c4 c5
        float2 bb = bp[0];
        float4 w0 = w4[j][0];             // B0..B3   (LDS broadcast)
        float4 w1 = w4[j][1];             // B4,B5,silu,pad
        acc0 += a.x * w0.x + a.y * w0.y + a.z * w0.z + a.w * w0.w
              + b.x * w1.x + b.y * w1.y + bb.x * w1.z;
        acc1 += b.z * w0.x + b.w * w0.y + c.x * w0.z + c.y * w0.w
              + c.z * w1.x + c.w * w1.y + bb.y * w1.z;
        cp += OUT_FEAT * N_BASIS / 4;
        bp += OUT_FEAT / 2;
    }
    float2* pp = (float2*)(partials + (size_t)blockIdx.y * OUT_FEAT + i0);
    pp[0] = make_float2(acc0, acc1);
}

// ---------------- deterministic two-stage reduce ----------------
__global__ void kan_reduce1_kernel(const float* __restrict__ partials,
                                   float* __restrict__ tmp) {
    int i = blockIdx.x * 256 + threadIdx.x;
    int g = blockIdx.y;
    float acc = 0.0f;
#pragma unroll
    for (int c = 0; c < NCHUNK / G1; ++c)
        acc += partials[(size_t)(g * (NCHUNK / G1) + c) * OUT_FEAT + i];
    tmp[(size_t)g * OUT_FEAT + i] = acc;
}

__global__ void kan_reduce2_kernel(const float* __restrict__ tmp,
                                   float* __restrict__ out) {
    int i = blockIdx.x * 256 + threadIdx.x;
    float acc = 0.0f;
#pragma unroll
    for (int g = 0; g < G1; ++g)
        acc += tmp[(size_t)g * OUT_FEAT + i];
    out[i] = acc;
}

extern "C" void kernel_launch(void* const* d_in, const int* in_sizes, int n_in,
                              void* d_out, int out_size, void* d_ws, size_t ws_size,
                              hipStream_t stream) {
    const float* x      = (const float*)d_in[0];   // [4096]
    const float* coeffs = (const float*)d_in[1];   // [4096][2048][6]
    const float* bw     = (const float*)d_in[2];   // [4096][2048]
    float* out = (float*)d_out;                    // [2048] fp32

    float* partials = (float*)d_ws;                          // NCHUNK*2048 floats (2 MB)
    float* tmp      = partials + (size_t)NCHUNK * OUT_FEAT;  // G1*2048 floats (128 KB)

    dim3 grid(OUT_FEAT / IBLK, NCHUNK);            // (4, 256) = 1024 blocks
    kan_partial_kernel<<<grid, TI, 0, stream>>>(coeffs, bw, x, partials);

    dim3 rgrid(OUT_FEAT / 256, G1);                // (8, 16) = 128 blocks
    kan_reduce1_kernel<<<rgrid, 256, 0, stream>>>(partials, tmp);

    kan_reduce2_kernel<<<OUT_FEAT / 256, 256, 0, stream>>>(tmp, out);
}